// Round 1
// 1342.347 us; speedup vs baseline: 1.1600x; 1.1600x over previous
//
#include <hip/hip_runtime.h>

// Problem constants (from reference)
#define NN 50000      // nodes
#define NE 300000     // edges
#define FEA 64        // edge feature dim
#define HD 256        // hidden
#define NG 256        // graphs
#define NL 4          // layers
#define OD 128        // out dim
#define SCB ((NN + 255) / 256)   // scan blocks = 196

typedef unsigned short u16;
typedef unsigned int u32;
typedef __attribute__((ext_vector_type(8))) short short8;
typedef __attribute__((ext_vector_type(4))) float f32x4;

__device__ __forceinline__ u16 f2h(float f) {
    union { _Float16 h; u16 u; } v; v.h = (_Float16)f; return v.u;
}
__device__ __forceinline__ float h2f(u16 u) {
    union { u16 u; _Float16 h; } v; v.u = u; return (float)v.h;
}

// global -> LDS direct DMA, 16B per lane. LDS dest must be the wave-uniform
// base (HW adds lane*16); the global source is per-lane, so swizzled LDS
// layouts are achieved by inverse-swizzling the SOURCE address (m104/m173).
typedef const __attribute__((address_space(1))) unsigned int gas_u32;
typedef __attribute__((address_space(3))) unsigned int las_u32;
__device__ __forceinline__ void gld16(const void* g, void* l) {
    __builtin_amdgcn_global_load_lds((gas_u32*)g, (las_u32*)l, 16, 0, 0);
}

// ---------------------------------------------------------------------------
// Fused edge kernel: per block, 64 sorted edges x full 256 cols.
//   T1 = relu(eattrS @ W1 + b1)      (K=64, LDS only)
//   e  = T1 @ W2 + b2                (K=256 as 8x32 chunks, double-buffered,
//                                     staged via global_load_lds, 1 barrier/chunk)
//   msg = relu(e + xh[src])          (xh rows DMA-gathered, overlapped)
//   aggr += segmented-sum(msg)       (per-block run reduction, ~1 atomic/node)
// LDS: bufW 32KB (W1 / 2x16KB W2 halves / xh gather) + bufT 32KB (eattr/T1/msg).
// ---------------------------------------------------------------------------
__global__ __launch_bounds__(256, 2) void edge_k(
    const u16* __restrict__ eattrS, const u16* __restrict__ W1t,
    const float* __restrict__ bb1, const u16* __restrict__ W2t,
    const float* __restrict__ bb2,
    const int* __restrict__ srcI, const int* __restrict__ dstI,
    const u16* __restrict__ xh, float* __restrict__ aggr)
{
    __shared__ __align__(16) u16 bufW[256 * 64];   // 32768 B
    __shared__ __align__(16) u16 bufT[64 * 256];   // 32768 B
    __shared__ int dstL[64];
    __shared__ int srcL[64];
    const int tid = threadIdx.x;
    const int lane = tid & 63;
    const int w = tid >> 6;
    const int q = lane >> 4, c15 = lane & 15;
    const int e0 = blockIdx.x * 64;
    const int wb = tid & ~63;      // wave-uniform lane-0 tid

    if (tid < 64) {
        int er = e0 + tid;
        int erc = er < NE ? er : NE - 1;
        dstL[tid] = (er < NE) ? dstI[erc] : -1;
        srcL[tid] = srcI[erc];
    }
    // stage eattr tile (64 x 64) into bufT via DMA, 3-bit swizzle on source
#pragma unroll
    for (int it = 0; it < 2; ++it) {
        const int i = it * 256 + tid;
        const int m = i >> 3, kb = i & 7;
        int row = e0 + m; if (row > NE - 1) row = NE - 1;
        gld16(eattrS + (size_t)row * FEA + ((kb ^ (m & 7)) * 8),
              &bufT[(it * 256 + wb) * 8]);
    }
    // stage W1 (256 x 64) into bufW via DMA
#pragma unroll
    for (int it = 0; it < 8; ++it) {
        const int i = it * 256 + tid;
        const int n = i >> 3, kb = i & 7;
        gld16(W1t + (size_t)n * FEA + ((kb ^ (n & 7)) * 8),
              &bufW[(it * 256 + wb) * 8]);
    }
    __syncthreads();

    // GEMM1: acc1[64 edges][w*64 + 64 cols], K=64
    f32x4 acc1[4][4];
#pragma unroll
    for (int i = 0; i < 4; ++i)
#pragma unroll
        for (int j = 0; j < 4; ++j) acc1[i][j] = (f32x4)0.0f;
#pragma unroll
    for (int s = 0; s < 2; ++s) {
        short8 af[4], bf[4];
#pragma unroll
        for (int t = 0; t < 4; ++t) {
            const int kga = s * 4 + q;
            const int mm = t * 16 + c15;
            af[t] = *(const short8*)&bufT[mm * 64 + ((kga ^ (mm & 7)) * 8)];
            const int nn = w * 64 + t * 16 + c15;
            bf[t] = *(const short8*)&bufW[nn * 64 + ((kga ^ (nn & 7)) * 8)];
        }
        __builtin_amdgcn_s_setprio(1);
#pragma unroll
        for (int tm = 0; tm < 4; ++tm)
#pragma unroll
            for (int tn = 0; tn < 4; ++tn)
                acc1[tm][tn] = __builtin_amdgcn_mfma_f32_16x16x32_f16(
                    af[tm], bf[tn], acc1[tm][tn], 0, 0, 0);
        __builtin_amdgcn_s_setprio(0);
    }
    __syncthreads();   // all reads of bufT(eattr)/bufW(W1) done

    // W2 chunk staging: 256 n x 32 k half-buffers (16KB), 2-bit-ish swizzle
    auto stageW2 = [&](int cc) {
        const int k0c = cc * 32;
        const int hB = (cc & 1) * 1024;   // 16B-chunk base of half
#pragma unroll
        for (int it = 0; it < 4; ++it) {
            const int i = it * 256 + tid;
            const int n = i >> 2, j = i & 3;
            gld16(W2t + (size_t)n * HD + k0c + ((j ^ ((n >> 1) & 3)) * 8),
                  &bufW[(hB + it * 256 + wb) * 8]);
        }
    };
    stageW2(0);   // chunk-0 DMA flies under the T1 epilogue

    // T1 = relu(acc1 + b1) -> bufT as [64 rows][256 k], swizzled
    {
        float b1f[4];
#pragma unroll
        for (int tn = 0; tn < 4; ++tn)
            b1f[tn] = bb1[w * 64 + tn * 16 + c15];
#pragma unroll
        for (int tm = 0; tm < 4; ++tm)
#pragma unroll
            for (int tn = 0; tn < 4; ++tn) {
                const int col = w * 64 + tn * 16 + c15;
                const int kb = col >> 3;
#pragma unroll
                for (int r = 0; r < 4; ++r) {
                    const int row = tm * 16 + q * 4 + r;
                    float v = acc1[tm][tn][r] + b1f[tn];
                    v = v > 0.0f ? v : 0.0f;
                    bufT[row * 256 + ((kb ^ (row & 7)) * 8) + (col & 7)] = f2h(v);
                }
            }
    }
    __syncthreads();   // T1 visible + chunk0 drained

    // GEMM2: acc2 = T1 @ W2, K=256 as 8 chunks of 32, double-buffered.
    // Prefetch chunk c+1 (or gather rows 0..31 at c=7) before chunk-c MFMAs.
    f32x4 acc2[4][4];
#pragma unroll
    for (int i = 0; i < 4; ++i)
#pragma unroll
        for (int j = 0; j < 4; ++j) acc2[i][j] = (f32x4)0.0f;
#pragma unroll
    for (int c = 0; c < 8; ++c) {
        if (c < 7) {
            stageW2(c + 1);
        } else {
            // c=7 reads half1; half0 is free -> gather xh rows 0..31 there
#pragma unroll
            for (int it = 0; it < 4; ++it) {
                const int i = it * 256 + tid;
                const int row = i >> 5, ch = i & 31;
                gld16(xh + (size_t)srcL[row] * HD + ch * 8,
                      &bufW[(it * 256 + wb) * 8]);
            }
        }
        short8 af[4], bf[4];
        const u16* hp = &bufW[(c & 1) * 8192];
#pragma unroll
        for (int t = 0; t < 4; ++t) {
            const int mm = t * 16 + c15;
            const int kbg = c * 4 + q;
            af[t] = *(const short8*)&bufT[mm * 256 + ((kbg ^ (mm & 7)) * 8)];
            const int nn = w * 64 + t * 16 + c15;
            bf[t] = *(const short8*)&hp[nn * 32 + ((q ^ ((nn >> 1) & 3)) * 8)];
        }
        __builtin_amdgcn_s_setprio(1);
#pragma unroll
        for (int tm = 0; tm < 4; ++tm)
#pragma unroll
            for (int tn = 0; tn < 4; ++tn)
                acc2[tm][tn] = __builtin_amdgcn_mfma_f32_16x16x32_f16(
                    af[tm], bf[tn], acc2[tm][tn], 0, 0, 0);
        __builtin_amdgcn_s_setprio(0);
        __syncthreads();   // drains this iteration's prefetch too
    }

    // gather xh rows 32..63 into half1 (now free)
#pragma unroll
    for (int it = 0; it < 4; ++it) {
        const int i = 1024 + it * 256 + tid;
        const int row = i >> 5, ch = i & 31;
        gld16(xh + (size_t)srcL[row] * HD + ch * 8,
              &bufW[(1024 + it * 256 + wb) * 8]);
    }
    float b2f[4];
#pragma unroll
    for (int tn = 0; tn < 4; ++tn)
        b2f[tn] = bb2[w * 64 + tn * 16 + c15];
    __syncthreads();   // drain gather-hi

    // msg = relu(acc2 + b2 + xh_gather) -> bufT [64][256] fp16 (unswizzled)
#pragma unroll
    for (int tm = 0; tm < 4; ++tm)
#pragma unroll
        for (int r = 0; r < 4; ++r) {
            const int row = tm * 16 + q * 4 + r;
            if (e0 + row < NE) {
#pragma unroll
                for (int tn = 0; tn < 4; ++tn) {
                    const int col = w * 64 + tn * 16 + c15;
                    float v = acc2[tm][tn][r] + b2f[tn]
                            + h2f(bufW[row * 256 + col]);
                    v = v > 0.0f ? v : 0.0f;
                    bufT[row * 256 + col] = f2h(v);
                }
            }
        }
    __syncthreads();

    // segmented reduction: thread t = col t, walk sorted rows, 1 atomic per run
    {
        const int hiR = (NE - e0 < 64) ? (NE - e0) : 64;
        float s = 0.0f;
        int cur = dstL[0];
        for (int rI = 0; rI < hiR; ++rI) {
            const int d = dstL[rI];
            if (d != cur) {
                if (s != 0.0f) unsafeAtomicAdd(&aggr[(size_t)cur * HD + tid], s);
                cur = d; s = 0.0f;
            }
            s += h2f(bufT[rI * 256 + tid]);
        }
        if (cur >= 0 && s != 0.0f)
            unsafeAtomicAdd(&aggr[(size_t)cur * HD + tid], s);
    }
}

// ---------------------------------------------------------------------------
// Fused node kernel: per block, 64 nodes x 256 cols.
//   h0 = (1+eps)*x + aggr          (computed in A-staging, fp16 to LDS)
//   T2 = relu(h0 @ M1 + b1)        (K=256 as 8x32 double-buffered DMA chunks)
//   hb = relu(T2 @ M2 + b2)        -> store + BN sum/sumsq atomics
// ---------------------------------------------------------------------------
__global__ __launch_bounds__(256, 2) void node_k(
    const u16* __restrict__ xh, const float* __restrict__ aggr,
    const float* __restrict__ epsv, int l,
    const u16* __restrict__ M1t, const float* __restrict__ mb1,
    const u16* __restrict__ M2t, const float* __restrict__ mb2,
    u16* __restrict__ hb, float* __restrict__ bns, float* __restrict__ bnq)
{
    __shared__ __align__(16) u16 bufW[256 * 64];   // 32768 B, 2x16KB halves
    __shared__ __align__(16) u16 bufT[64 * 256];   // 32768 B
    const int tid = threadIdx.x;
    const int lane = tid & 63;
    const int w = tid >> 6;
    const int q = lane >> 4, c15 = lane & 15;
    const int n0b = blockIdx.x * 64;
    const float e1 = 1.0f + epsv[l];
    const int wb = tid & ~63;

    auto stageM = [&](const u16* Mt, int cc) {
        const int k0c = cc * 32;
        const int hB = (cc & 1) * 1024;
#pragma unroll
        for (int it = 0; it < 4; ++it) {
            const int i = it * 256 + tid;
            const int n = i >> 2, j = i & 3;
            gld16(Mt + (size_t)n * HD + k0c + ((j ^ ((n >> 1) & 3)) * 8),
                  &bufW[(hB + it * 256 + wb) * 8]);
        }
    };
    stageM(M1t, 0);   // chunk-0 DMA flies under the A-tile build

    // stage A tile: h0 = (1+eps)*xh + aggr, 64 rows x 256 k, swizzled
#pragma unroll
    for (int it = 0; it < 8; ++it) {
        const int i = it * 256 + tid;        // 0..2047
        const int m = i >> 5, kb = i & 31;
        int row = n0b + m; if (row > NN - 1) row = NN - 1;
        const size_t base = (size_t)row * HD + kb * 8;
        short8 xv = *(const short8*)(xh + base);
        float4 a0 = *(const float4*)(aggr + base);
        float4 a1 = *(const float4*)(aggr + base + 4);
        u16 o[8];
        o[0] = f2h(e1 * h2f((u16)xv[0]) + a0.x);
        o[1] = f2h(e1 * h2f((u16)xv[1]) + a0.y);
        o[2] = f2h(e1 * h2f((u16)xv[2]) + a0.z);
        o[3] = f2h(e1 * h2f((u16)xv[3]) + a0.w);
        o[4] = f2h(e1 * h2f((u16)xv[4]) + a1.x);
        o[5] = f2h(e1 * h2f((u16)xv[5]) + a1.y);
        o[6] = f2h(e1 * h2f((u16)xv[6]) + a1.z);
        o[7] = f2h(e1 * h2f((u16)xv[7]) + a1.w);
        *(short8*)&bufT[m * 256 + ((kb ^ (m & 7)) * 8)] = *(short8*)o;
    }
    __syncthreads();

    // GEMM1: T2acc = h0 @ M1, K=256 (8 chunks, double-buffered)
    f32x4 acc1[4][4];
#pragma unroll
    for (int i = 0; i < 4; ++i)
#pragma unroll
        for (int j = 0; j < 4; ++j) acc1[i][j] = (f32x4)0.0f;
#pragma unroll
    for (int c = 0; c < 8; ++c) {
        if (c < 7) stageM(M1t, c + 1);
        else       stageM(M2t, 0);     // prefetch GEMM2 chunk0 into free half0
        short8 af[4], bf[4];
        const u16* hp = &bufW[(c & 1) * 8192];
#pragma unroll
        for (int t = 0; t < 4; ++t) {
            const int mm = t * 16 + c15;
            const int kbg = c * 4 + q;
            af[t] = *(const short8*)&bufT[mm * 256 + ((kbg ^ (mm & 7)) * 8)];
            const int nn = w * 64 + t * 16 + c15;
            bf[t] = *(const short8*)&hp[nn * 32 + ((q ^ ((nn >> 1) & 3)) * 8)];
        }
        __builtin_amdgcn_s_setprio(1);
#pragma unroll
        for (int tm = 0; tm < 4; ++tm)
#pragma unroll
            for (int tn = 0; tn < 4; ++tn)
                acc1[tm][tn] = __builtin_amdgcn_mfma_f32_16x16x32_f16(
                    af[tm], bf[tn], acc1[tm][tn], 0, 0, 0);
        __builtin_amdgcn_s_setprio(0);
        __syncthreads();
    }

    // T2 = relu(acc1 + b1) -> bufT (overwrite A tile), swizzled
    {
        float b1f[4];
#pragma unroll
        for (int tn = 0; tn < 4; ++tn)
            b1f[tn] = mb1[w * 64 + tn * 16 + c15];
#pragma unroll
        for (int tm = 0; tm < 4; ++tm)
#pragma unroll
            for (int tn = 0; tn < 4; ++tn) {
                const int col = w * 64 + tn * 16 + c15;
                const int kb = col >> 3;
#pragma unroll
                for (int r = 0; r < 4; ++r) {
                    const int row = tm * 16 + q * 4 + r;
                    float v = acc1[tm][tn][r] + b1f[tn];
                    v = v > 0.0f ? v : 0.0f;
                    bufT[row * 256 + ((kb ^ (row & 7)) * 8) + (col & 7)] = f2h(v);
                }
            }
    }
    __syncthreads();

    // GEMM2: acc2 = T2 @ M2, K=256 (8 chunks, double-buffered)
    f32x4 acc2[4][4];
#pragma unroll
    for (int i = 0; i < 4; ++i)
#pragma unroll
        for (int j = 0; j < 4; ++j) acc2[i][j] = (f32x4)0.0f;
#pragma unroll
    for (int c = 0; c < 8; ++c) {
        if (c < 7) stageM(M2t, c + 1);
        short8 af[4], bf[4];
        const u16* hp = &bufW[(c & 1) * 8192];
#pragma unroll
        for (int t = 0; t < 4; ++t) {
            const int mm = t * 16 + c15;
            const int kbg = c * 4 + q;
            af[t] = *(const short8*)&bufT[mm * 256 + ((kbg ^ (mm & 7)) * 8)];
            const int nn = w * 64 + t * 16 + c15;
            bf[t] = *(const short8*)&hp[nn * 32 + ((q ^ ((nn >> 1) & 3)) * 8)];
        }
        __builtin_amdgcn_s_setprio(1);
#pragma unroll
        for (int tm = 0; tm < 4; ++tm)
#pragma unroll
            for (int tn = 0; tn < 4; ++tn)
                acc2[tm][tn] = __builtin_amdgcn_mfma_f32_16x16x32_f16(
                    af[tm], bf[tn], acc2[tm][tn], 0, 0, 0);
        __builtin_amdgcn_s_setprio(0);
        __syncthreads();
    }

    // EPI: hb = relu(acc2 + b2) store + BN stats
    float b2f[4];
#pragma unroll
    for (int tn = 0; tn < 4; ++tn)
        b2f[tn] = mb2[w * 64 + tn * 16 + c15];
    float ps[4] = {0, 0, 0, 0}, pq[4] = {0, 0, 0, 0};
#pragma unroll
    for (int tm = 0; tm < 4; ++tm) {
#pragma unroll
        for (int r = 0; r < 4; ++r) {
            const int grow = n0b + tm * 16 + q * 4 + r;
            if (grow < NN) {
#pragma unroll
                for (int tn = 0; tn < 4; ++tn) {
                    const int col = w * 64 + tn * 16 + c15;
                    float v = acc2[tm][tn][r] + b2f[tn];
                    v = v > 0.0f ? v : 0.0f;
                    hb[(size_t)grow * HD + col] = f2h(v);
                    ps[tn] += v; pq[tn] += v * v;
                }
            }
        }
    }
#pragma unroll
    for (int tn = 0; tn < 4; ++tn) {
        float s = ps[tn], sq = pq[tn];
        s += __shfl_down(s, 32, 64);  sq += __shfl_down(sq, 32, 64);
        s += __shfl_down(s, 16, 64);  sq += __shfl_down(sq, 16, 64);
        if (q == 0) {
            const int col = w * 64 + tn * 16 + c15;
            unsafeAtomicAdd(&bns[col], s);
            unsafeAtomicAdd(&bnq[col], sq);
        }
    }
}

// --------------------------- small helper kernels ---------------------------

// fp32 [L,K,N] -> fp16 transposed [L,N,K]
__global__ void transpose_k(const float* __restrict__ in, u16* __restrict__ oh,
                            int Kw, int Nw) {
    int i = blockIdx.x * blockDim.x + threadIdx.x;
    int tot = NL * Kw * Nw;
    if (i < tot) {
        int l = i / (Kw * Nw), rem = i % (Kw * Nw);
        int k = rem / Nw, n = rem % Nw;
        oh[(size_t)l * Kw * Nw + (size_t)n * Kw + k] = f2h(in[i]);
    }
}

__global__ void cvt_k(const float* __restrict__ in, u16* __restrict__ outh, int tot) {
    int i = blockIdx.x * blockDim.x + threadIdx.x;
    if (i < tot) outh[i] = f2h(in[i]);
}

// gather eattr rows into sorted order, fp32 -> fp16
__global__ void egather_k(const float* __restrict__ eattr, const int* __restrict__ perm,
                          u16* __restrict__ eattrS) {
    int i = blockIdx.x * blockDim.x + threadIdx.x;
    if (i < NE * FEA) {
        int row = i >> 6, k = i & 63;
        eattrS[i] = f2h(eattr[(size_t)perm[row] * FEA + k]);
    }
}

__global__ void zero_layer_k(float* __restrict__ aggr, float* __restrict__ bns,
                             float* __restrict__ bnq) {
    int i = blockIdx.x * blockDim.x + threadIdx.x;
    if (i < NN * HD) aggr[i] = 0.0f;
    if (i < HD) { bns[i] = 0.0f; bnq[i] = 0.0f; }
}

__global__ void zerof_k(float* __restrict__ p, int n) {
    int i = blockIdx.x * blockDim.x + threadIdx.x;
    if (i < n) p[i] = 0.0f;
}

__global__ void bnfin_k(const float* __restrict__ bns, const float* __restrict__ bnq,
                        const float* __restrict__ gamma, const float* __restrict__ beta,
                        int l, float* __restrict__ ab) {
    int c = threadIdx.x;
    float mu = bns[c] * (1.0f / (float)NN);
    float var = bnq[c] * (1.0f / (float)NN) - mu * mu;
    if (var < 0.0f) var = 0.0f;
    float a = gamma[l * HD + c] * rsqrtf(var + 1e-5f);
    float b = beta[l * HD + c] - mu * a;
    ab[c] = a; ab[HD + c] = b;
}

// BN-apply fused with graph mean-pool accumulation (batch is sorted):
// block = 64 consecutive nodes, thread t = col t; run-reduction + 1 atomic/run.
__global__ void bnapply_k(const u16* __restrict__ hb, const float* __restrict__ ab,
                          const int* __restrict__ batch, u16* __restrict__ xh,
                          float* __restrict__ pooled, int l) {
    const int t = threadIdx.x;
    const int n0 = blockIdx.x * 64;
    const float a = ab[t], b = ab[HD + t];
    const int hi = (NN - n0 < 64) ? (NN - n0) : 64;
    float s = 0.0f;
    int cur = batch[n0];
    for (int r = 0; r < hi; ++r) {
        const size_t idx = (size_t)(n0 + r) * HD + t;
        float v = a * h2f(hb[idx]) + b;
        xh[idx] = f2h(v);
        const int g = batch[n0 + r];
        if (g != cur) {
            unsafeAtomicAdd(&pooled[(size_t)cur * (NL * HD) + l * HD + t], s);
            s = 0.0f; cur = g;
        }
        s += v;
    }
    unsafeAtomicAdd(&pooled[(size_t)cur * (NL * HD) + l * HD + t], s);
}

// ---- edge counting-sort by dst (hierarchical scan) ----

__global__ void zeroi_k(int* __restrict__ a, int n) {
    int i = blockIdx.x * blockDim.x + threadIdx.x;
    if (i < n) a[i] = 0;
}

__global__ void hist_k(const int* __restrict__ dst, int* __restrict__ hist) {
    int e = blockIdx.x * blockDim.x + threadIdx.x;
    if (e < NE) atomicAdd(&hist[dst[e]], 1);
}

__global__ void sumblk_k(const int* __restrict__ hist, int* __restrict__ psum) {
    __shared__ int red[256];
    int b = blockIdx.x, t = threadIdx.x, i = b * 256 + t;
    red[t] = (i < NN) ? hist[i] : 0;
    __syncthreads();
    for (int o = 128; o > 0; o >>= 1) {
        if (t < o) red[t] += red[t + o];
        __syncthreads();
    }
    if (t == 0) psum[b] = red[0];
}

__global__ void scanblk_k(int* __restrict__ psum) {
    __shared__ int sc[256];
    int t = threadIdx.x;
    int v = (t < SCB) ? psum[t] : 0;
    sc[t] = v; __syncthreads();
    for (int o = 1; o < 256; o <<= 1) {
        int x = (t >= o) ? sc[t - o] : 0;
        __syncthreads(); sc[t] += x; __syncthreads();
    }
    if (t < SCB) psum[t] = sc[t] - v;   // exclusive
}

__global__ void scanfin_k(const int* __restrict__ hist, const int* __restrict__ psum,
                          int* __restrict__ rowptr) {
    __shared__ int sc[256];
    int b = blockIdx.x, t = threadIdx.x, i = b * 256 + t;
    int v = (i < NN) ? hist[i] : 0;
    sc[t] = v; __syncthreads();
    for (int o = 1; o < 256; o <<= 1) {
        int x = (t >= o) ? sc[t - o] : 0;
        __syncthreads(); sc[t] += x; __syncthreads();
    }
    if (i < NN) rowptr[i] = psum[b] + sc[t] - v;
    if (i == NN - 1) rowptr[NN] = psum[b] + sc[t];
}

__global__ void copyi_k(const int* __restrict__ src, int* __restrict__ dst, int n) {
    int i = blockIdx.x * blockDim.x + threadIdx.x;
    if (i < n) dst[i] = src[i];
}

__global__ void scatter_k(const int* __restrict__ dst, int* __restrict__ next,
                          int* __restrict__ perm) {
    int e = blockIdx.x * blockDim.x + threadIdx.x;
    if (e < NE) {
        int p = atomicAdd(&next[dst[e]], 1);
        perm[p] = e;
    }
}

__global__ void permsd_k(const int* __restrict__ eidx, const int* __restrict__ perm,
                         int* __restrict__ srcS, int* __restrict__ dstS) {
    int i = blockIdx.x * blockDim.x + threadIdx.x;
    if (i < NE) {
        int e = perm[i];
        srcS[i] = eidx[e];
        dstS[i] = eidx[NE + e];
    }
}

// ---- graph pooling counts ----

__global__ void zcnt_k(int* __restrict__ cnts) {
    if (threadIdx.x < NG) cnts[threadIdx.x] = 0;
}

__global__ void count_k(const int* __restrict__ batch, int* __restrict__ cnts) {
    int i = blockIdx.x * blockDim.x + threadIdx.x;
    if (i < NN) atomicAdd(&cnts[batch[i]], 1);
}

__global__ void fc_k(const float* __restrict__ pooled, const int* __restrict__ cnts,
                     const float* __restrict__ W1, const float* __restrict__ b1,
                     const float* __restrict__ W4, const float* __restrict__ b4,
                     float* __restrict__ out) {
    __shared__ float pl[NL * HD];
    __shared__ float hm[HD];
    int g = blockIdx.x, t = threadIdx.x;
    const float inv = 1.0f / fmaxf((float)cnts[g], 1.0f);
#pragma unroll
    for (int j = 0; j < 4; ++j)
        pl[t + j * 256] = pooled[(size_t)g * 1024 + t + j * 256] * inv;
    __syncthreads();
    float a = b1[t];
    for (int k = 0; k < 1024; ++k) a += pl[k] * W1[k * 256 + t];
    hm[t] = a > 0.0f ? a : 0.0f;
    __syncthreads();
    if (t < OD) {
        float o = b4[t];
        for (int k = 0; k < 256; ++k) o += hm[k] * W4[k * OD + t];
        out[g * OD + t] = o;
    }
}

// ---------------------------------------------------------------------------

extern "C" void kernel_launch(void* const* d_in, const int* in_sizes, int n_in,
                              void* d_out, int out_size, void* d_ws, size_t ws_size,
                              hipStream_t stream) {
    const float* x_in  = (const float*)d_in[0];
    const int*   eidx  = (const int*)d_in[1];
    const float* eattr = (const float*)d_in[2];
    const int*   batch = (const int*)d_in[3];
    const float* bW1   = (const float*)d_in[4];
    const float* bb1   = (const float*)d_in[5];
    const float* bW2   = (const float*)d_in[6];
    const float* bb2   = (const float*)d_in[7];
    const float* mW1   = (const float*)d_in[8];
    const float* mb1   = (const float*)d_in[9];
    const float* mW2   = (const float*)d_in[10];
    const float* mb2   = (const float*)d_in[11];
    const float* epsv  = (const float*)d_in[12];
    const float* gamma = (const float*)d_in[13];
    const float* beta  = (const float*)d_in[14];
    const float* fc1W  = (const float*)d_in[15];
    const float* fc1b  = (const float*)d_in[16];
    const float* fc4W  = (const float*)d_in[17];
    const float* fc4b  = (const float*)d_in[18];
    float* out = (float*)d_out;
    (void)in_sizes; (void)n_in; (void)out_size; (void)ws_size;

    // ---- workspace carve (~148 MB; ~156 MB proven safe in round 4) ----
    size_t off = 0;
    auto alloc = [&](size_t bytes) -> char* {
        char* r = (char*)d_ws + off;
        off = (off + bytes + 255) & ~(size_t)255;
        return r;
    };
    u16*   xh   = (u16*)alloc((size_t)NN * HD * 2);    // 25.6 MB node feats, fp16
    float* aggr = (float*)alloc((size_t)NN * HD * 4);  // 51.2 MB aggregate, fp32
    u16*   hb   = (u16*)alloc((size_t)NN * HD * 2);    // 25.6 MB MLP out pre-BN
    u16*   eattrS = (u16*)alloc((size_t)NE * FEA * 2); // 38.4 MB sorted fp16 eattr
    u16*   W1t  = (u16*)alloc((size_t)NL * FEA * HD * 2);
    u16*   W2t  = (u16*)alloc((size_t)NL * HD * HD * 2);
    u16*   M1t  = (u16*)alloc((size_t)NL * HD * HD * 2);
    u16*   M2t  = (u16*)alloc((size_t)NL * HD * HD * 2);
    float* bns  = (float*)alloc(HD * 4);
    float* bnq  = (float*)alloc(HD * 4);
    float* ab   = (float*)alloc(2 * HD * 4);
    int*   cnts = (int*)alloc(NG * 4);
    float* pooled = (float*)alloc((size_t)NG * NL * HD * 4);
    int*   hist  = (int*)alloc((size_t)NN * 4);        // also reused as `next`
    int*   psum  = (int*)alloc((size_t)SCB * 4);
    int*   rowptr = (int*)alloc((size_t)(NN + 1) * 4);
    int*   perm  = (int*)alloc((size_t)NE * 4);
    int*   srcS  = (int*)alloc((size_t)NE * 4);
    int*   dstS  = (int*)alloc((size_t)NE * 4);

    const int NEL = NN * HD;
    const int EB = (NEL + 255) / 256;
    const int NEB = (NE + 255) / 256;

    // weights: fp32 -> fp16, transposed to [N,K]
    transpose_k<<<(NL * FEA * HD + 255) / 256, 256, 0, stream>>>(bW1, W1t, FEA, HD);
    transpose_k<<<(NL * HD * HD + 255) / 256, 256, 0, stream>>>(bW2, W2t, HD, HD);
    transpose_k<<<(NL * HD * HD + 255) / 256, 256, 0, stream>>>(mW1, M1t, HD, HD);
    transpose_k<<<(NL * HD * HD + 255) / 256, 256, 0, stream>>>(mW2, M2t, HD, HD);

    cvt_k<<<EB, 256, 0, stream>>>(x_in, xh, NEL);

    // counting-sort edges by dst: hist -> hierarchical scan -> scatter perm
    zeroi_k<<<(NN + 255) / 256, 256, 0, stream>>>(hist, NN);
    hist_k<<<NEB, 256, 0, stream>>>(eidx + NE, hist);
    sumblk_k<<<SCB, 256, 0, stream>>>(hist, psum);
    scanblk_k<<<1, 256, 0, stream>>>(psum);
    scanfin_k<<<SCB, 256, 0, stream>>>(hist, psum, rowptr);
    copyi_k<<<(NN + 255) / 256, 256, 0, stream>>>(rowptr, hist, NN);   // hist = next
    scatter_k<<<NEB, 256, 0, stream>>>(eidx + NE, hist, perm);
    permsd_k<<<NEB, 256, 0, stream>>>(eidx, perm, srcS, dstS);
    egather_k<<<(NE * FEA + 255) / 256, 256, 0, stream>>>(eattr, perm, eattrS);

    zcnt_k<<<1, 256, 0, stream>>>(cnts);
    count_k<<<(NN + 255) / 256, 256, 0, stream>>>(batch, cnts);
    zerof_k<<<(NG * NL * HD + 255) / 256, 256, 0, stream>>>(pooled, NG * NL * HD);

    const int EGB = (NE + 63) / 64;    // 4688 edge blocks
    const int NGB = (NN + 63) / 64;    // 782 node blocks

    for (int l = 0; l < NL; ++l) {
        zero_layer_k<<<EB, 256, 0, stream>>>(aggr, bns, bnq);
        edge_k<<<EGB, 256, 0, stream>>>(
            eattrS, W1t + (size_t)l * FEA * HD, bb1 + l * HD,
            W2t + (size_t)l * HD * HD, bb2 + l * HD,
            srcS, dstS, xh, aggr);
        node_k<<<NGB, 256, 0, stream>>>(
            xh, aggr, epsv, l,
            M1t + (size_t)l * HD * HD, mb1 + l * HD,
            M2t + (size_t)l * HD * HD, mb2 + l * HD,
            hb, bns, bnq);
        bnfin_k<<<1, HD, 0, stream>>>(bns, bnq, gamma, beta, l, ab);
        bnapply_k<<<NGB, 256, 0, stream>>>(hb, ab, batch, xh, pooled, l);
    }
    fc_k<<<NG, 256, 0, stream>>>(pooled, cnts, fc1W, fc1b, fc4W, fc4b, out);
}

// Round 4
// 1268.060 us; speedup vs baseline: 1.2280x; 1.0586x over previous
//
#include <hip/hip_runtime.h>

// Problem constants (from reference)
#define NN 50000      // nodes
#define NE 300000     // edges
#define FEA 64        // edge feature dim
#define HD 256        // hidden
#define NG 256        // graphs
#define NL 4          // layers
#define OD 128        // out dim
#define SCB ((NN + 255) / 256)   // scan blocks = 196

typedef unsigned short u16;
typedef unsigned int u32;
typedef __attribute__((ext_vector_type(8))) short short8;
typedef __attribute__((ext_vector_type(4))) short s16x4;
typedef __attribute__((ext_vector_type(4))) float f32x4;

__device__ __forceinline__ u16 f2h(float f) {
    union { _Float16 h; u16 u; } v; v.h = (_Float16)f; return v.u;
}
__device__ __forceinline__ float h2f(u16 u) {
    union { u16 u; _Float16 h; } v; v.u = u; return (float)v.h;
}

// global -> LDS direct DMA, 16B per lane. LDS dest is wave-uniform base
// (HW adds lane*16); per-lane global source carries any swizzle (m104/m173).
typedef const __attribute__((address_space(1))) unsigned int gas_u32;
typedef __attribute__((address_space(3))) unsigned int las_u32;
__device__ __forceinline__ void gld16(const void* g, void* l) {
    __builtin_amdgcn_global_load_lds((gas_u32*)g, (las_u32*)l, 16, 0, 0);
}

// ---------------------------------------------------------------------------
// Fused edge kernel: per block, 64 sorted edges x full 256 cols.
//   T1 = relu(eattrS @ W1 + b1)      GEMM1 operand-swapped so the C-frag reg
//                                    index runs along k -> b64 packed T1 write
//   e  = T1 @ W2 + b2                (K=256 as 8x32 DMA chunks, dbuf)
//   msg = relu(e + xh[src])          xh row-major gathered (linear DMA),
//                                    scalar reads; msg written col-major b64
//   aggr += segmented-sum(msg)       vectorized short8 walk, scalar dst loads
// ---------------------------------------------------------------------------
__global__ __launch_bounds__(256, 2) void edge_k(
    const u16* __restrict__ eattrS, const u16* __restrict__ W1t,
    const float* __restrict__ bb1, const u16* __restrict__ W2t,
    const float* __restrict__ bb2,
    const int* __restrict__ srcI, const int* __restrict__ dstI,
    const u16* __restrict__ xh, float* __restrict__ aggr)
{
    __shared__ __align__(16) u16 bufW[256 * 64];   // 32768 B
    __shared__ __align__(16) u16 bufT[64 * 256];   // 32768 B
    __shared__ int srcL[64];
    const int tid = threadIdx.x;
    const int lane = tid & 63;
    const int w = tid >> 6;
    const int q = lane >> 4, c15 = lane & 15;
    const int e0 = blockIdx.x * 64;
    const int wb = tid & ~63;      // wave-uniform lane-0 tid

    if (tid < 64) {
        int er = e0 + tid;
        int erc = er < NE ? er : NE - 1;
        srcL[tid] = srcI[erc];
    }
    // stage eattr tile (64 x 64) into bufT via DMA, 3-bit swizzle on source
#pragma unroll
    for (int it = 0; it < 2; ++it) {
        const int i = it * 256 + tid;
        const int m = i >> 3, kb = i & 7;
        int row = e0 + m; if (row > NE - 1) row = NE - 1;
        gld16(eattrS + (size_t)row * FEA + ((kb ^ (m & 7)) * 8),
              &bufT[(it * 256 + wb) * 8]);
    }
    // stage W1 (256 x 64) into bufW via DMA
#pragma unroll
    for (int it = 0; it < 8; ++it) {
        const int i = it * 256 + tid;
        const int n = i >> 3, kb = i & 7;
        gld16(W1t + (size_t)n * FEA + ((kb ^ (n & 7)) * 8),
              &bufW[(it * 256 + wb) * 8]);
    }
    __syncthreads();

    // GEMM1 (swapped): acc1[tm][tn] -> C[m = W1col tile tm][n = edge tile tn]
    f32x4 acc1[4][4];
#pragma unroll
    for (int i = 0; i < 4; ++i)
#pragma unroll
        for (int j = 0; j < 4; ++j) acc1[i][j] = (f32x4)0.0f;
#pragma unroll
    for (int s = 0; s < 2; ++s) {
        short8 af[4], bf[4];
#pragma unroll
        for (int t = 0; t < 4; ++t) {
            const int kga = s * 4 + q;
            const int mm = t * 16 + c15;
            af[t] = *(const short8*)&bufT[mm * 64 + ((kga ^ (mm & 7)) * 8)];
            const int nn = w * 64 + t * 16 + c15;
            bf[t] = *(const short8*)&bufW[nn * 64 + ((kga ^ (nn & 7)) * 8)];
        }
        __builtin_amdgcn_s_setprio(1);
#pragma unroll
        for (int tm = 0; tm < 4; ++tm)
#pragma unroll
            for (int tn = 0; tn < 4; ++tn)
                acc1[tm][tn] = __builtin_amdgcn_mfma_f32_16x16x32_f16(
                    bf[tm], af[tn], acc1[tm][tn], 0, 0, 0);
        __builtin_amdgcn_s_setprio(0);
    }
    __syncthreads();   // all reads of bufT(eattr)/bufW(W1) done

    // W2 chunk staging: 256 n x 32 k half-buffers (16KB)
    auto stageW2 = [&](int cc) {
        const int k0c = cc * 32;
        const int hB = (cc & 1) * 1024;   // 16B-chunk base of half
#pragma unroll
        for (int it = 0; it < 4; ++it) {
            const int i = it * 256 + tid;
            const int n = i >> 2, j = i & 3;
            gld16(W2t + (size_t)n * HD + k0c + ((j ^ ((n >> 1) & 3)) * 8),
                  &bufW[(hB + it * 256 + wb) * 8]);
        }
    };
    stageW2(0);   // chunk-0 DMA flies under the T1 epilogue

    // T1 epi: thread holds k = w*64+tm*16+q*4+r for edge = tn*16+c15
    // -> pack 4 f16, b64 write into row-major swizzled bufT[edge][k]
    {
#pragma unroll
        for (int tm = 0; tm < 4; ++tm) {
            const float4 b1v = *(const float4*)(bb1 + w * 64 + tm * 16 + q * 4);
            const int kb = w * 8 + tm * 2 + (q >> 1);
#pragma unroll
            for (int tn = 0; tn < 4; ++tn) {
                const int edge = tn * 16 + c15;
                s16x4 o;
#pragma unroll
                for (int r = 0; r < 4; ++r) {
                    float v = acc1[tm][tn][r] + ((const float*)&b1v)[r];
                    v = v > 0.0f ? v : 0.0f;
                    o[r] = (short)f2h(v);
                }
                *(s16x4*)((char*)bufT + edge * 512 +
                          ((kb ^ (edge & 7)) << 4) + ((q & 1) << 3)) = o;
            }
        }
    }
    __syncthreads();   // T1 visible + chunk0 drained

    // GEMM2: acc2 = T1 @ W2 (not swapped): C[m=edge][n=outcol]
    f32x4 acc2[4][4];
#pragma unroll
    for (int i = 0; i < 4; ++i)
#pragma unroll
        for (int j = 0; j < 4; ++j) acc2[i][j] = (f32x4)0.0f;
#pragma unroll
    for (int c = 0; c < 8; ++c) {
        if (c < 7) {
            stageW2(c + 1);
        } else {
            // c=7 reads half1; half0 free -> gather xh rows 0..31,
            // row-major linear [row][256] (validated layout)
#pragma unroll
            for (int it = 0; it < 4; ++it) {
                const int i = it * 256 + tid;   // 0..1023
                const int row = i >> 5, ch = i & 31;
                gld16(xh + (size_t)srcL[row] * HD + ch * 8,
                      &bufW[(it * 256 + wb) * 8]);
            }
        }
        short8 af[4], bf[4];
        const u16* hp = &bufW[(c & 1) * 8192];
#pragma unroll
        for (int t = 0; t < 4; ++t) {
            const int mm = t * 16 + c15;
            const int kbg = c * 4 + q;
            af[t] = *(const short8*)&bufT[mm * 256 + ((kbg ^ (mm & 7)) * 8)];
            const int nn = w * 64 + t * 16 + c15;
            bf[t] = *(const short8*)&hp[nn * 32 + ((q ^ ((nn >> 1) & 3)) * 8)];
        }
        __builtin_amdgcn_s_setprio(1);
#pragma unroll
        for (int tm = 0; tm < 4; ++tm)
#pragma unroll
            for (int tn = 0; tn < 4; ++tn)
                acc2[tm][tn] = __builtin_amdgcn_mfma_f32_16x16x32_f16(
                    af[tm], bf[tn], acc2[tm][tn], 0, 0, 0);
        __builtin_amdgcn_s_setprio(0);
        __syncthreads();   // drains this iteration's prefetch too
    }

    // gather xh rows 32..63 into half1 (now free), row-major linear
#pragma unroll
    for (int it = 0; it < 4; ++it) {
        const int i = 1024 + it * 256 + tid;
        const int row = i >> 5, ch = i & 31;
        gld16(xh + (size_t)srcL[row] * HD + ch * 8,
              &bufW[(1024 + it * 256 + wb) * 8]);
    }
    float b2f[4];
#pragma unroll
    for (int tn = 0; tn < 4; ++tn)
        b2f[tn] = bb2[w * 64 + tn * 16 + c15];
    __syncthreads();   // drain gather-hi; all T1 reads complete

    // msg = relu(acc2 + b2 + xh_src): scalar xh reads (row-major gather),
    // write col-major swizzled bufT[col][row] as packed b64 (4 rows)
#pragma unroll
    for (int tm = 0; tm < 4; ++tm) {
        const int rc = tm * 2 + (q >> 1);
#pragma unroll
        for (int tn = 0; tn < 4; ++tn) {
            const int col = w * 64 + tn * 16 + c15;
            s16x4 o;
#pragma unroll
            for (int r = 0; r < 4; ++r) {
                const int row = tm * 16 + q * 4 + r;
                float v = acc2[tm][tn][r] + b2f[tn]
                        + h2f(bufW[row * 256 + col]);
                v = v > 0.0f ? v : 0.0f;
                o[r] = (short)f2h(v);
            }
            *(s16x4*)((char*)bufT + col * 128 +
                      ((rc ^ (col & 7)) << 4) + ((q & 1) << 3)) = o;
        }
    }
    __syncthreads();

    // segmented reduction: thread t = col t, walk 64 rows via 8x short8,
    // dst lookups are wave-uniform scalar loads (off the LDS pipe)
    {
        const char* bT = (const char*)bufT;
        float s = 0.0f;
        int cur = dstI[e0];
#pragma unroll
        for (int j = 0; j < 8; ++j) {
            short8 m8 = *(const short8*)(bT + tid * 128 + ((j ^ (tid & 7)) << 4));
#pragma unroll
            for (int si = 0; si < 8; ++si) {
                const int er = e0 + j * 8 + si;
                const int d = (er < NE) ? dstI[er] : -1;
                if (d != cur) {
                    if (cur >= 0 && s != 0.0f)
                        unsafeAtomicAdd(&aggr[(size_t)cur * HD + tid], s);
                    cur = d; s = 0.0f;
                }
                s += h2f((u16)m8[si]);
            }
        }
        if (cur >= 0 && s != 0.0f)
            unsafeAtomicAdd(&aggr[(size_t)cur * HD + tid], s);
    }
}

// ---------------------------------------------------------------------------
// Fused node kernel: per block, 64 nodes x 256 cols.
//   h0 = (1+eps)*x + aggr          (computed in A-staging, fp16 to LDS)
//   T2 = relu(h0 @ M1 + b1)        GEMM1 swapped -> b64 packed T2 write
//   hb = relu(T2 @ M2 + b2)        -> store + BN sum/sumsq atomics
// ---------------------------------------------------------------------------
__global__ __launch_bounds__(256, 2) void node_k(
    const u16* __restrict__ xh, const float* __restrict__ aggr,
    const float* __restrict__ epsv, int l,
    const u16* __restrict__ M1t, const float* __restrict__ mb1,
    const u16* __restrict__ M2t, const float* __restrict__ mb2,
    u16* __restrict__ hb, float* __restrict__ bns, float* __restrict__ bnq)
{
    __shared__ __align__(16) u16 bufW[256 * 64];   // 32768 B, 2x16KB halves
    __shared__ __align__(16) u16 bufT[64 * 256];   // 32768 B
    const int tid = threadIdx.x;
    const int lane = tid & 63;
    const int w = tid >> 6;
    const int q = lane >> 4, c15 = lane & 15;
    const int n0b = blockIdx.x * 64;
    const float e1 = 1.0f + epsv[l];
    const int wb = tid & ~63;

    auto stageM = [&](const u16* Mt, int cc) {
        const int k0c = cc * 32;
        const int hB = (cc & 1) * 1024;
#pragma unroll
        for (int it = 0; it < 4; ++it) {
            const int i = it * 256 + tid;
            const int n = i >> 2, j = i & 3;
            gld16(Mt + (size_t)n * HD + k0c + ((j ^ ((n >> 1) & 3)) * 8),
                  &bufW[(hB + it * 256 + wb) * 8]);
        }
    };
    stageM(M1t, 0);   // chunk-0 DMA flies under the A-tile build

    // stage A tile: h0 = (1+eps)*xh + aggr, 64 rows x 256 k, swizzled
#pragma unroll
    for (int it = 0; it < 8; ++it) {
        const int i = it * 256 + tid;        // 0..2047
        const int m = i >> 5, kb = i & 31;
        int row = n0b + m; if (row > NN - 1) row = NN - 1;
        const size_t base = (size_t)row * HD + kb * 8;
        short8 xv = *(const short8*)(xh + base);
        float4 a0 = *(const float4*)(aggr + base);
        float4 a1 = *(const float4*)(aggr + base + 4);
        u16 o[8];
        o[0] = f2h(e1 * h2f((u16)xv[0]) + a0.x);
        o[1] = f2h(e1 * h2f((u16)xv[1]) + a0.y);
        o[2] = f2h(e1 * h2f((u16)xv[2]) + a0.z);
        o[3] = f2h(e1 * h2f((u16)xv[3]) + a0.w);
        o[4] = f2h(e1 * h2f((u16)xv[4]) + a1.x);
        o[5] = f2h(e1 * h2f((u16)xv[5]) + a1.y);
        o[6] = f2h(e1 * h2f((u16)xv[6]) + a1.z);
        o[7] = f2h(e1 * h2f((u16)xv[7]) + a1.w);
        *(short8*)&bufT[m * 256 + ((kb ^ (m & 7)) * 8)] = *(short8*)o;
    }
    __syncthreads();

    // GEMM1 (swapped): acc1[tm][tn] -> C[m = M1col tile tm][n = node tile tn]
    f32x4 acc1[4][4];
#pragma unroll
    for (int i = 0; i < 4; ++i)
#pragma unroll
        for (int j = 0; j < 4; ++j) acc1[i][j] = (f32x4)0.0f;
#pragma unroll
    for (int c = 0; c < 8; ++c) {
        if (c < 7) stageM(M1t, c + 1);
        else       stageM(M2t, 0);     // prefetch GEMM2 chunk0 into free half0
        short8 af[4], bf[4];
        const u16* hp = &bufW[(c & 1) * 8192];
#pragma unroll
        for (int t = 0; t < 4; ++t) {
            const int mm = t * 16 + c15;
            const int kbg = c * 4 + q;
            af[t] = *(const short8*)&bufT[mm * 256 + ((kbg ^ (mm & 7)) * 8)];
            const int nn = w * 64 + t * 16 + c15;
            bf[t] = *(const short8*)&hp[nn * 32 + ((q ^ ((nn >> 1) & 3)) * 8)];
        }
        __builtin_amdgcn_s_setprio(1);
#pragma unroll
        for (int tm = 0; tm < 4; ++tm)
#pragma unroll
            for (int tn = 0; tn < 4; ++tn)
                acc1[tm][tn] = __builtin_amdgcn_mfma_f32_16x16x32_f16(
                    bf[tm], af[tn], acc1[tm][tn], 0, 0, 0);
        __builtin_amdgcn_s_setprio(0);
        __syncthreads();
    }

    // T2 epi: pack 4 f16 along k, b64 write into swizzled bufT[node][k]
    {
#pragma unroll
        for (int tm = 0; tm < 4; ++tm) {
            const float4 b1v = *(const float4*)(mb1 + w * 64 + tm * 16 + q * 4);
            const int kb = w * 8 + tm * 2 + (q >> 1);
#pragma unroll
            for (int tn = 0; tn < 4; ++tn) {
                const int node = tn * 16 + c15;
                s16x4 o;
#pragma unroll
                for (int r = 0; r < 4; ++r) {
                    float v = acc1[tm][tn][r] + ((const float*)&b1v)[r];
                    v = v > 0.0f ? v : 0.0f;
                    o[r] = (short)f2h(v);
                }
                *(s16x4*)((char*)bufT + node * 512 +
                          ((kb ^ (node & 7)) << 4) + ((q & 1) << 3)) = o;
            }
        }
    }
    __syncthreads();

    // GEMM2: acc2 = T2 @ M2 (not swapped): C[m=node][n=outcol]
    f32x4 acc2[4][4];
#pragma unroll
    for (int i = 0; i < 4; ++i)
#pragma unroll
        for (int j = 0; j < 4; ++j) acc2[i][j] = (f32x4)0.0f;
#pragma unroll
    for (int c = 0; c < 8; ++c) {
        if (c < 7) stageM(M2t, c + 1);
        short8 af[4], bf[4];
        const u16* hp = &bufW[(c & 1) * 8192];
#pragma unroll
        for (int t = 0; t < 4; ++t) {
            const int mm = t * 16 + c15;
            const int kbg = c * 4 + q;
            af[t] = *(const short8*)&bufT[mm * 256 + ((kbg ^ (mm & 7)) * 8)];
            const int nn = w * 64 + t * 16 + c15;
            bf[t] = *(const short8*)&hp[nn * 32 + ((q ^ ((nn >> 1) & 3)) * 8)];
        }
        __builtin_amdgcn_s_setprio(1);
#pragma unroll
        for (int tm = 0; tm < 4; ++tm)
#pragma unroll
            for (int tn = 0; tn < 4; ++tn)
                acc2[tm][tn] = __builtin_amdgcn_mfma_f32_16x16x32_f16(
                    af[tm], bf[tn], acc2[tm][tn], 0, 0, 0);
        __builtin_amdgcn_s_setprio(0);
        __syncthreads();
    }

    // EPI: hb = relu(acc2 + b2) store + BN stats
    float b2f[4];
#pragma unroll
    for (int tn = 0; tn < 4; ++tn)
        b2f[tn] = mb2[w * 64 + tn * 16 + c15];
    float ps[4] = {0, 0, 0, 0}, pq[4] = {0, 0, 0, 0};
#pragma unroll
    for (int tm = 0; tm < 4; ++tm) {
#pragma unroll
        for (int r = 0; r < 4; ++r) {
            const int grow = n0b + tm * 16 + q * 4 + r;
            if (grow < NN) {
#pragma unroll
                for (int tn = 0; tn < 4; ++tn) {
                    const int col = w * 64 + tn * 16 + c15;
                    float v = acc2[tm][tn][r] + b2f[tn];
                    v = v > 0.0f ? v : 0.0f;
                    hb[(size_t)grow * HD + col] = f2h(v);
                    ps[tn] += v; pq[tn] += v * v;
                }
            }
        }
    }
#pragma unroll
    for (int tn = 0; tn < 4; ++tn) {
        float s = ps[tn], sq = pq[tn];
        s += __shfl_down(s, 32, 64);  sq += __shfl_down(sq, 32, 64);
        s += __shfl_down(s, 16, 64);  sq += __shfl_down(sq, 16, 64);
        if (q == 0) {
            const int col = w * 64 + tn * 16 + c15;
            unsafeAtomicAdd(&bns[col], s);
            unsafeAtomicAdd(&bnq[col], sq);
        }
    }
}

// --------------------------- small helper kernels ---------------------------

// fp32 [L,K,N] -> fp16 transposed [L,N,K]
__global__ void transpose_k(const float* __restrict__ in, u16* __restrict__ oh,
                            int Kw, int Nw) {
    int i = blockIdx.x * blockDim.x + threadIdx.x;
    int tot = NL * Kw * Nw;
    if (i < tot) {
        int l = i / (Kw * Nw), rem = i % (Kw * Nw);
        int k = rem / Nw, n = rem % Nw;
        oh[(size_t)l * Kw * Nw + (size_t)n * Kw + k] = f2h(in[i]);
    }
}

__global__ void cvt_k(const float* __restrict__ in, u16* __restrict__ outh, int tot) {
    int i = blockIdx.x * blockDim.x + threadIdx.x;
    if (i < tot) outh[i] = f2h(in[i]);
}

// gather eattr rows into sorted order, fp32 -> fp16
__global__ void egather_k(const float* __restrict__ eattr, const int* __restrict__ perm,
                          u16* __restrict__ eattrS) {
    int i = blockIdx.x * blockDim.x + threadIdx.x;
    if (i < NE * FEA) {
        int row = i >> 6, k = i & 63;
        eattrS[i] = f2h(eattr[(size_t)perm[row] * FEA + k]);
    }
}

__global__ void zero_layer_k(float* __restrict__ aggr, float* __restrict__ bns,
                             float* __restrict__ bnq) {
    int i = blockIdx.x * blockDim.x + threadIdx.x;
    if (i < NN * HD) aggr[i] = 0.0f;
    if (i < HD) { bns[i] = 0.0f; bnq[i] = 0.0f; }
}

__global__ void zerof_k(float* __restrict__ p, int n) {
    int i = blockIdx.x * blockDim.x + threadIdx.x;
    if (i < n) p[i] = 0.0f;
}

__global__ void bnfin_k(const float* __restrict__ bns, const float* __restrict__ bnq,
                        const float* __restrict__ gamma, const float* __restrict__ beta,
                        int l, float* __restrict__ ab) {
    int c = threadIdx.x;
    float mu = bns[c] * (1.0f / (float)NN);
    float var = bnq[c] * (1.0f / (float)NN) - mu * mu;
    if (var < 0.0f) var = 0.0f;
    float a = gamma[l * HD + c] * rsqrtf(var + 1e-5f);
    float b = beta[l * HD + c] - mu * a;
    ab[c] = a; ab[HD + c] = b;
}

// BN-apply fused with graph mean-pool accumulation (batch is sorted):
// block = 64 consecutive nodes, thread t = col t; run-reduction + 1 atomic/run.
__global__ void bnapply_k(const u16* __restrict__ hb, const float* __restrict__ ab,
                          const int* __restrict__ batch, u16* __restrict__ xh,
                          float* __restrict__ pooled, int l) {
    const int t = threadIdx.x;
    const int n0 = blockIdx.x * 64;
    const float a = ab[t], b = ab[HD + t];
    const int hi = (NN - n0 < 64) ? (NN - n0) : 64;
    float s = 0.0f;
    int cur = batch[n0];
    for (int r = 0; r < hi; ++r) {
        const size_t idx = (size_t)(n0 + r) * HD + t;
        float v = a * h2f(hb[idx]) + b;
        xh[idx] = f2h(v);
        const int g = batch[n0 + r];
        if (g != cur) {
            unsafeAtomicAdd(&pooled[(size_t)cur * (NL * HD) + l * HD + t], s);
            s = 0.0f; cur = g;
        }
        s += v;
    }
    unsafeAtomicAdd(&pooled[(size_t)cur * (NL * HD) + l * HD + t], s);
}

// ---- edge counting-sort by dst (hierarchical scan) ----

__global__ void zeroi_k(int* __restrict__ a, int n) {
    int i = blockIdx.x * blockDim.x + threadIdx.x;
    if (i < n) a[i] = 0;
}

__global__ void hist_k(const int* __restrict__ dst, int* __restrict__ hist) {
    int e = blockIdx.x * blockDim.x + threadIdx.x;
    if (e < NE) atomicAdd(&hist[dst[e]], 1);
}

__global__ void sumblk_k(const int* __restrict__ hist, int* __restrict__ psum) {
    __shared__ int red[256];
    int b = blockIdx.x, t = threadIdx.x, i = b * 256 + t;
    red[t] = (i < NN) ? hist[i] : 0;
    __syncthreads();
    for (int o = 128; o > 0; o >>= 1) {
        if (t < o) red[t] += red[t + o];
        __syncthreads();
    }
    if (t == 0) psum[b] = red[0];
}

__global__ void scanblk_k(int* __restrict__ psum) {
    __shared__ int sc[256];
    int t = threadIdx.x;
    int v = (t < SCB) ? psum[t] : 0;
    sc[t] = v; __syncthreads();
    for (int o = 1; o < 256; o <<= 1) {
        int x = (t >= o) ? sc[t - o] : 0;
        __syncthreads(); sc[t] += x; __syncthreads();
    }
    if (t < SCB) psum[t] = sc[t] - v;   // exclusive
}

__global__ void scanfin_k(const int* __restrict__ hist, const int* __restrict__ psum,
                          int* __restrict__ rowptr) {
    __shared__ int sc[256];
    int b = blockIdx.x, t = threadIdx.x, i = b * 256 + t;
    int v = (i < NN) ? hist[i] : 0;
    sc[t] = v; __syncthreads();
    for (int o = 1; o < 256; o <<= 1) {
        int x = (t >= o) ? sc[t - o] : 0;
        __syncthreads(); sc[t] += x; __syncthreads();
    }
    if (i < NN) rowptr[i] = psum[b] + sc[t] - v;
    if (i == NN - 1) rowptr[NN] = psum[b] + sc[t];
}

__global__ void copyi_k(const int* __restrict__ src, int* __restrict__ dst, int n) {
    int i = blockIdx.x * blockDim.x + threadIdx.x;
    if (i < n) dst[i] = src[i];
}

__global__ void scatter_k(const int* __restrict__ dst, int* __restrict__ next,
                          int* __restrict__ perm) {
    int e = blockIdx.x * blockDim.x + threadIdx.x;
    if (e < NE) {
        int p = atomicAdd(&next[dst[e]], 1);
        perm[p] = e;
    }
}

__global__ void permsd_k(const int* __restrict__ eidx, const int* __restrict__ perm,
                         int* __restrict__ srcS, int* __restrict__ dstS) {
    int i = blockIdx.x * blockDim.x + threadIdx.x;
    if (i < NE) {
        int e = perm[i];
        srcS[i] = eidx[e];
        dstS[i] = eidx[NE + e];
    }
}

// ---- graph pooling counts ----

__global__ void zcnt_k(int* __restrict__ cnts) {
    if (threadIdx.x < NG) cnts[threadIdx.x] = 0;
}

__global__ void count_k(const int* __restrict__ batch, int* __restrict__ cnts) {
    int i = blockIdx.x * blockDim.x + threadIdx.x;
    if (i < NN) atomicAdd(&cnts[batch[i]], 1);
}

__global__ void fc_k(const float* __restrict__ pooled, const int* __restrict__ cnts,
                     const float* __restrict__ W1, const float* __restrict__ b1,
                     const float* __restrict__ W4, const float* __restrict__ b4,
                     float* __restrict__ out) {
    __shared__ float pl[NL * HD];
    __shared__ float hm[HD];
    int g = blockIdx.x, t = threadIdx.x;
    const float inv = 1.0f / fmaxf((float)cnts[g], 1.0f);
#pragma unroll
    for (int j = 0; j < 4; ++j)
        pl[t + j * 256] = pooled[(size_t)g * 1024 + t + j * 256] * inv;
    __syncthreads();
    float a = b1[t];
    for (int k = 0; k < 1024; ++k) a += pl[k] * W1[k * 256 + t];
    hm[t] = a > 0.0f ? a : 0.0f;
    __syncthreads();
    if (t < OD) {
        float o = b4[t];
        for (int k = 0; k < 256; ++k) o += hm[k] * W4[k * OD + t];
        out[g * OD + t] = o;
    }
}

// ---------------------------------------------------------------------------

extern "C" void kernel_launch(void* const* d_in, const int* in_sizes, int n_in,
                              void* d_out, int out_size, void* d_ws, size_t ws_size,
                              hipStream_t stream) {
    const float* x_in  = (const float*)d_in[0];
    const int*   eidx  = (const int*)d_in[1];
    const float* eattr = (const float*)d_in[2];
    const int*   batch = (const int*)d_in[3];
    const float* bW1   = (const float*)d_in[4];
    const float* bb1   = (const float*)d_in[5];
    const float* bW2   = (const float*)d_in[6];
    const float* bb2   = (const float*)d_in[7];
    const float* mW1   = (const float*)d_in[8];
    const float* mb1   = (const float*)d_in[9];
    const float* mW2   = (const float*)d_in[10];
    const float* mb2   = (const float*)d_in[11];
    const float* epsv  = (const float*)d_in[12];
    const float* gamma = (const float*)d_in[13];
    const float* beta  = (const float*)d_in[14];
    const float* fc1W  = (const float*)d_in[15];
    const float* fc1b  = (const float*)d_in[16];
    const float* fc4W  = (const float*)d_in[17];
    const float* fc4b  = (const float*)d_in[18];
    float* out = (float*)d_out;
    (void)in_sizes; (void)n_in; (void)out_size; (void)ws_size;

    // ---- workspace carve (~148 MB; ~156 MB proven safe in round 4) ----
    size_t off = 0;
    auto alloc = [&](size_t bytes) -> char* {
        char* r = (char*)d_ws + off;
        off = (off + bytes + 255) & ~(size_t)255;
        return r;
    };
    u16*   xh   = (u16*)alloc((size_t)NN * HD * 2);    // 25.6 MB node feats, fp16
    float* aggr = (float*)alloc((size_t)NN * HD * 4);  // 51.2 MB aggregate, fp32
    u16*   hb   = (u16*)alloc((size_t)NN * HD * 2);    // 25.6 MB MLP out pre-BN
    u16*   eattrS = (u16*)alloc((size_t)NE * FEA * 2); // 38.4 MB sorted fp16 eattr
    u16*   W1t  = (u16*)alloc((size_t)NL * FEA * HD * 2);
    u16*   W2t  = (u16*)alloc((size_t)NL * HD * HD * 2);
    u16*   M1t  = (u16*)alloc((size_t)NL * HD * HD * 2);
    u16*   M2t  = (u16*)alloc((size_t)NL * HD * HD * 2);
    float* bns  = (float*)alloc(HD * 4);
    float* bnq  = (float*)alloc(HD * 4);
    float* ab   = (float*)alloc(2 * HD * 4);
    int*   cnts = (int*)alloc(NG * 4);
    float* pooled = (float*)alloc((size_t)NG * NL * HD * 4);
    int*   hist  = (int*)alloc((size_t)NN * 4);        // also reused as `next`
    int*   psum  = (int*)alloc((size_t)SCB * 4);
    int*   rowptr = (int*)alloc((size_t)(NN + 1) * 4);
    int*   perm  = (int*)alloc((size_t)NE * 4);
    int*   srcS  = (int*)alloc((size_t)NE * 4);
    int*   dstS  = (int*)alloc((size_t)NE * 4);

    const int NEL = NN * HD;
    const int EB = (NEL + 255) / 256;
    const int NEB = (NE + 255) / 256;

    // weights: fp32 -> fp16, transposed to [N,K]
    transpose_k<<<(NL * FEA * HD + 255) / 256, 256, 0, stream>>>(bW1, W1t, FEA, HD);
    transpose_k<<<(NL * HD * HD + 255) / 256, 256, 0, stream>>>(bW2, W2t, HD, HD);
    transpose_k<<<(NL * HD * HD + 255) / 256, 256, 0, stream>>>(mW1, M1t, HD, HD);
    transpose_k<<<(NL * HD * HD + 255) / 256, 256, 0, stream>>>(mW2, M2t, HD, HD);

    cvt_k<<<EB, 256, 0, stream>>>(x_in, xh, NEL);

    // counting-sort edges by dst: hist -> hierarchical scan -> scatter perm
    zeroi_k<<<(NN + 255) / 256, 256, 0, stream>>>(hist, NN);
    hist_k<<<NEB, 256, 0, stream>>>(eidx + NE, hist);
    sumblk_k<<<SCB, 256, 0, stream>>>(hist, psum);
    scanblk_k<<<1, 256, 0, stream>>>(psum);
    scanfin_k<<<SCB, 256, 0, stream>>>(hist, psum, rowptr);
    copyi_k<<<(NN + 255) / 256, 256, 0, stream>>>(rowptr, hist, NN);   // hist = next
    scatter_k<<<NEB, 256, 0, stream>>>(eidx + NE, hist, perm);
    permsd_k<<<NEB, 256, 0, stream>>>(eidx, perm, srcS, dstS);
    egather_k<<<(NE * FEA + 255) / 256, 256, 0, stream>>>(eattr, perm, eattrS);

    zcnt_k<<<1, 256, 0, stream>>>(cnts);
    count_k<<<(NN + 255) / 256, 256, 0, stream>>>(batch, cnts);
    zerof_k<<<(NG * NL * HD + 255) / 256, 256, 0, stream>>>(pooled, NG * NL * HD);

    const int EGB = (NE + 63) / 64;    // 4688 edge blocks
    const int NGB = (NN + 63) / 64;    // 782 node blocks

    for (int l = 0; l < NL; ++l) {
        zero_layer_k<<<EB, 256, 0, stream>>>(aggr, bns, bnq);
        edge_k<<<EGB, 256, 0, stream>>>(
            eattrS, W1t + (size_t)l * FEA * HD, bb1 + l * HD,
            W2t + (size_t)l * HD * HD, bb2 + l * HD,
            srcS, dstS, xh, aggr);
        node_k<<<NGB, 256, 0, stream>>>(
            xh, aggr, epsv, l,
            M1t + (size_t)l * HD * HD, mb1 + l * HD,
            M2t + (size_t)l * HD * HD, mb2 + l * HD,
            hb, bns, bnq);
        bnfin_k<<<1, HD, 0, stream>>>(bns, bnq, gamma, beta, l, ab);
        bnapply_k<<<NGB, 256, 0, stream>>>(hb, ab, batch, xh, pooled, l);
    }
    fc_k<<<NG, 256, 0, stream>>>(pooled, cnts, fc1W, fc1b, fc4W, fc4b, out);
}